// Round 8
// baseline (156.811 us; speedup 1.0000x reference)
//
#include <hip/hip_runtime.h>
#include <float.h>

#define B 16
#define H 256
#define W 256
#define C 64
#define T 16            // rows per h-tile
#define NT (H / T)      // 16 h-tiles

typedef float f4 __attribute__((ext_vector_type(4)));

__device__ __forceinline__ f4 fmax4(f4 a, f4 b)
{
    f4 r;
    r.x = fmaxf(a.x, b.x);
    r.y = fmaxf(a.y, b.y);
    r.z = fmaxf(a.z, b.z);
    r.w = fmaxf(a.w, b.w);
    return r;
}

__device__ __forceinline__ f4 shfl_down4(f4 a, int d)
{
    f4 r;
    r.x = __shfl_down(a.x, d, 64);
    r.y = __shfl_down(a.y, d, 64);
    r.z = __shfl_down(a.z, d, 64);
    r.w = __shfl_down(a.w, d, 64);
    return r;
}

// ---------------------------------------------------------------------------
// k_colscan: fused pass-1 + tile scan. One thread per (w, c-quad); scans its
// whole column (256 rows) in 16-row chunks, t descending, writing the
// EXCLUSIVE 16-row-granular h-suffix:
//   hSuf[b][t][w][c] = max over rows h >= (t+1)*16 of in[b,h,w,c]
// grid = B*16 = 256 blocks x 256 threads. 256 MiB read + 16 MiB write.
// 16 independent dwordx4 loads in flight per thread (4 waves/CU).
// Input loads PLAIN (seed L3 for k_fuse's re-read).
// ---------------------------------------------------------------------------
__global__ __launch_bounds__(256) void k_colscan(const float* __restrict__ in,
                                                 float* __restrict__ hSuf)
{
    int b   = blockIdx.x >> 4;
    int w16 = blockIdx.x & 15;
    int c4  = threadIdx.x & 15;
    int wl  = threadIdx.x >> 4;
    int w   = w16 * 16 + wl;

    const f4* ip = (const f4*)(in + ((size_t)b * H * W + w) * C) + c4;
    f4*       hp = (f4*)(hSuf + ((size_t)b * NT * W + w) * C) + c4;
    const size_t RS = (size_t)W * C / 4;   // 4096 f4 (one row / one tile slot)

    f4 run = {-FLT_MAX, -FLT_MAX, -FLT_MAX, -FLT_MAX};
    for (int t = NT - 1; t >= 0; --t) {
        f4 l[T];
#pragma unroll
        for (int hh = 0; hh < T; ++hh)
            l[hh] = ip[(size_t)(t * T + hh) * RS];
        hp[(size_t)t * RS] = run;          // exclusive suffix for this tile
        f4 m0 = fmax4(fmax4(fmax4(l[0],  l[1]),  fmax4(l[2],  l[3])),
                      fmax4(fmax4(l[4],  l[5]),  fmax4(l[6],  l[7])));
        f4 m1 = fmax4(fmax4(fmax4(l[8],  l[9]),  fmax4(l[10], l[11])),
                      fmax4(fmax4(l[12], l[13]), fmax4(l[14], l[15])));
        run = fmax4(run, fmax4(m0, m1));
    }
}

// ---------------------------------------------------------------------------
// k_fuse: final pass over one 16-row x full-W x full-C tile per block.
// 512 threads: c4 = tid&15, g = tid>>4 in [0,32); group g owns w = g*8+j.
// Wave wv = tid>>6 holds local groups gl = (tid>>4)&3.
// Per row (h descending):
//   hrun[j] = max(hrun[j], v[j])          (seeded from exclusive hSuf)
//   in-thread w-suffix over the 8 owned w
//   in-WAVE suffix over 4 local groups via 2 shfl_down rounds (no LDS)
//   1 LDS write (wave leader) + 1 barrier + <=7 cross-wave LDS reads
//   out = hrun + max(v, seed)             (non-temporal dwordx4 stores)
// Input loads NON-TEMPORAL: still hit L3 if resident, but don't re-allocate
// (no future reader) -> preserves the unread L3-resident portion.
// Per-row LDS slot -> ONE barrier per row. grid = B*NT = 256 blocks.
// ---------------------------------------------------------------------------
__global__ __launch_bounds__(512) void k_fuse(const float* __restrict__ in,
                                              const float* __restrict__ hSuf,
                                              float* __restrict__ out)
{
    __shared__ f4 exch[T][8][16];    // 32 KiB: [row][wave][c4]
    int b  = blockIdx.x >> 4;
    int t  = blockIdx.x & 15;
    int c4 = threadIdx.x & 15;
    int g  = threadIdx.x >> 4;       // 0..31
    int gl = g & 3;                  // local group within wave
    int wv = threadIdx.x >> 6;       // 0..7
    int wb = g * 8;

    const f4* hs = (const f4*)(hSuf + ((size_t)(b * NT + t) * W + wb) * C) + c4;
    f4 hrun[8];
#pragma unroll
    for (int j = 0; j < 8; ++j)
        hrun[j] = hs[j * 16];        // plain load: expect L2/L3 hit

    for (int hh = T - 1; hh >= 0; --hh) {
        const size_t roff = ((size_t)(b * H + t * T + hh) * W + wb) * (C / 4) + c4;
        const f4* row = (const f4*)in + roff;
        f4 v[8];
#pragma unroll
        for (int j = 0; j < 8; ++j)
            v[j] = __builtin_nontemporal_load(&row[j * 16]);
#pragma unroll
        for (int j = 0; j < 8; ++j) hrun[j] = fmax4(hrun[j], v[j]);
        // in-thread inclusive w-suffix over this group's 8 w
#pragma unroll
        for (int j = 6; j >= 0; --j) v[j] = fmax4(v[j], v[j + 1]);

        // in-wave inclusive suffix over the 4 local groups (lane stride 16)
        f4 s = v[0];                           // group total
        f4 tt = shfl_down4(s, 16);
        if (gl < 3) s = fmax4(s, tt);
        tt = shfl_down4(s, 32);
        if (gl < 2) s = fmax4(s, tt);
        // exclusive version for this thread's seed:
        f4 e = shfl_down4(s, 16);
        if (gl == 3) e = (f4){-FLT_MAX, -FLT_MAX, -FLT_MAX, -FLT_MAX};

        if (gl == 0) exch[hh][wv][c4] = s;     // wave total (groups 4wv..4wv+3)
        __syncthreads();
        f4 seed = e;
        for (int wp = wv + 1; wp < 8; ++wp)
            seed = fmax4(seed, exch[hh][wp][c4]);

        f4* orow = (f4*)out + roff;
#pragma unroll
        for (int j = 0; j < 8; ++j)
            __builtin_nontemporal_store(hrun[j] + fmax4(v[j], seed),
                                        &orow[j * 16]);
    }
}

// ---------------------------------------------------------------------------
// Fallback (no workspace): two serial-scan kernels, fully coalesced.
// ---------------------------------------------------------------------------
__global__ __launch_bounds__(256) void k_wscan(const float* __restrict__ in,
                                               float* __restrict__ out)
{
    int idx = blockIdx.x * 256 + threadIdx.x;
    int c  = idx & 63;
    int bh = idx >> 6;
    const float* p = in + (size_t)bh * W * C + c;
    float* q = out + (size_t)bh * W * C + c;
    float run = -FLT_MAX;
    for (int w = W - 1; w >= 0; --w) {
        run = fmaxf(run, p[w * C]);
        q[w * C] = run;
    }
}

__global__ __launch_bounds__(256) void k_hscan_add(const float* __restrict__ in,
                                                   float* __restrict__ out)
{
    int idx = blockIdx.x * 256 + threadIdx.x;
    int wc = idx & (W * C - 1);
    int b  = idx >> 14;
    const float* p = in + (size_t)b * H * W * C + wc;
    float* q = out + (size_t)b * H * W * C + wc;
    float run = -FLT_MAX;
    for (int h = H - 1; h >= 0; --h) {
        run = fmaxf(run, p[(size_t)h * W * C]);
        q[(size_t)h * W * C] += run;
    }
}

extern "C" void kernel_launch(void* const* d_in, const int* in_sizes, int n_in,
                              void* d_out, int out_size, void* d_ws, size_t ws_size,
                              hipStream_t stream)
{
    const float* in = (const float*)d_in[0];
    float* out = (float*)d_out;

    const size_t need = (size_t)B * NT * W * C * sizeof(float);   // 16 MiB

    if (ws_size >= need) {
        float* hSuf = (float*)d_ws;
        k_colscan<<<B * 16, 256, 0, stream>>>(in, hSuf);
        k_fuse<<<B * NT, 512, 0, stream>>>(in, hSuf, out);
    } else {
        k_wscan<<<B * H * C / 256, 256, 0, stream>>>(in, out);
        k_hscan_add<<<B * W * C / 256, 256, 0, stream>>>(in, out);
    }
}

// Round 9
// 146.117 us; speedup vs baseline: 1.0732x; 1.0732x over previous
//
#include <hip/hip_runtime.h>
#include <float.h>

#define B 16
#define H 256
#define W 256
#define C 64
#define T8 8            // rows per h-tile
#define NT (H / T8)     // 32 h-tiles

typedef float f4 __attribute__((ext_vector_type(4)));

__device__ __forceinline__ f4 fmax4(f4 a, f4 b)
{
    f4 r;
    r.x = fmaxf(a.x, b.x);
    r.y = fmaxf(a.y, b.y);
    r.z = fmaxf(a.z, b.z);
    r.w = fmaxf(a.w, b.w);
    return r;
}

__device__ __forceinline__ f4 shfl_down4(f4 a, int d)
{
    f4 r;
    r.x = __shfl_down(a.x, d, 64);
    r.y = __shfl_down(a.y, d, 64);
    r.z = __shfl_down(a.z, d, 64);
    r.w = __shfl_down(a.w, d, 64);
    return r;
}

// ---------------------------------------------------------------------------
// k_colscan (R7-exact): fused pass-1 + tile scan. One thread per (w, c-quad);
// scans its whole column (256 rows) in 8-row chunks, t descending, writing
// the EXCLUSIVE 8-row-granular h-suffix:
//   hSuf[b][t][w][c] = max over rows h >= (t+1)*8 of in[b,h,w,c]
// grid = B*16 = 256 blocks x 256 threads. 256 MiB read + 32 MiB write.
// 8 independent dwordx4 loads in flight per thread. Plain loads (seed L3).
// ---------------------------------------------------------------------------
__global__ __launch_bounds__(256) void k_colscan(const float* __restrict__ in,
                                                 float* __restrict__ hSuf)
{
    int b   = blockIdx.x >> 4;
    int w16 = blockIdx.x & 15;
    int c4  = threadIdx.x & 15;
    int wl  = threadIdx.x >> 4;
    int w   = w16 * 16 + wl;

    const f4* ip = (const f4*)(in + ((size_t)b * H * W + w) * C) + c4;
    f4*       hp = (f4*)(hSuf + ((size_t)b * NT * W + w) * C) + c4;
    const size_t RS = (size_t)W * C / 4;   // 4096 f4

    f4 run = {-FLT_MAX, -FLT_MAX, -FLT_MAX, -FLT_MAX};
    for (int t = NT - 1; t >= 0; --t) {
        f4 l[T8];
#pragma unroll
        for (int hh = 0; hh < T8; ++hh)
            l[hh] = ip[(size_t)(t * T8 + hh) * RS];
        hp[(size_t)t * RS] = run;          // exclusive suffix for this tile
        f4 m = fmax4(fmax4(fmax4(l[0], l[1]), fmax4(l[2], l[3])),
                     fmax4(fmax4(l[4], l[5]), fmax4(l[6], l[7])));
        run = fmax4(run, m);
    }
}

// ---------------------------------------------------------------------------
// k_fuse (R7-exact): final pass over one 8-row x full-W x full-C tile per
// block. 512 threads: c4 = tid&15, g = tid>>4 in [0,32); group g owns
// w = g*8+j. Wave wv = tid>>6 holds local groups gl = (tid>>4)&3.
// Per row (h descending):
//   hrun[j] = max(hrun[j], v[j])          (seeded from exclusive hSuf)
//   in-thread w-suffix over the 8 owned w
//   in-WAVE suffix over 4 local groups via 2 shfl_down rounds (no LDS)
//   1 LDS write (wave leader) + 1 barrier + <=7 cross-wave LDS reads
//   out = hrun + max(v, seed)             (non-temporal dwordx4 stores)
// PLAIN input loads (L2/L3 hits help; nt regressed in R8).
// Per-row LDS slot -> ONE barrier per row. grid = B*NT = 512 blocks.
// ---------------------------------------------------------------------------
__global__ __launch_bounds__(512) void k_fuse(const float* __restrict__ in,
                                              const float* __restrict__ hSuf,
                                              float* __restrict__ out)
{
    __shared__ f4 exch[T8][8][16];   // 16 KiB: [row][wave][c4]
    int b  = blockIdx.x >> 5;
    int t  = blockIdx.x & 31;
    int c4 = threadIdx.x & 15;
    int g  = threadIdx.x >> 4;       // 0..31
    int gl = g & 3;                  // local group within wave
    int wv = threadIdx.x >> 6;       // 0..7
    int wb = g * 8;

    const f4* hs = (const f4*)(hSuf + ((size_t)(b * NT + t) * W + wb) * C) + c4;
    f4 hrun[8];
#pragma unroll
    for (int j = 0; j < 8; ++j)
        hrun[j] = hs[j * 16];        // plain load: expect L2/L3 hit

    for (int hh = T8 - 1; hh >= 0; --hh) {
        const size_t roff = ((size_t)(b * H + t * T8 + hh) * W + wb) * (C / 4) + c4;
        const f4* row = (const f4*)in + roff;
        f4 v[8];
#pragma unroll
        for (int j = 0; j < 8; ++j) v[j] = row[j * 16];
#pragma unroll
        for (int j = 0; j < 8; ++j) hrun[j] = fmax4(hrun[j], v[j]);
        // in-thread inclusive w-suffix over this group's 8 w
#pragma unroll
        for (int j = 6; j >= 0; --j) v[j] = fmax4(v[j], v[j + 1]);

        // in-wave inclusive suffix over the 4 local groups (lane stride 16)
        f4 s = v[0];                           // group total
        f4 tt = shfl_down4(s, 16);
        if (gl < 3) s = fmax4(s, tt);
        tt = shfl_down4(s, 32);
        if (gl < 2) s = fmax4(s, tt);
        // exclusive version for this thread's seed:
        f4 e = shfl_down4(s, 16);
        if (gl == 3) e = (f4){-FLT_MAX, -FLT_MAX, -FLT_MAX, -FLT_MAX};

        if (gl == 0) exch[hh][wv][c4] = s;     // wave total (groups 4wv..4wv+3)
        __syncthreads();
        f4 seed = e;
        for (int wp = wv + 1; wp < 8; ++wp)
            seed = fmax4(seed, exch[hh][wp][c4]);

        f4* orow = (f4*)out + roff;
#pragma unroll
        for (int j = 0; j < 8; ++j)
            __builtin_nontemporal_store(hrun[j] + fmax4(v[j], seed),
                                        &orow[j * 16]);
    }
}

// ---------------------------------------------------------------------------
// Fallback (no workspace): two serial-scan kernels, fully coalesced.
// ---------------------------------------------------------------------------
__global__ __launch_bounds__(256) void k_wscan(const float* __restrict__ in,
                                               float* __restrict__ out)
{
    int idx = blockIdx.x * 256 + threadIdx.x;
    int c  = idx & 63;
    int bh = idx >> 6;
    const float* p = in + (size_t)bh * W * C + c;
    float* q = out + (size_t)bh * W * C + c;
    float run = -FLT_MAX;
    for (int w = W - 1; w >= 0; --w) {
        run = fmaxf(run, p[w * C]);
        q[w * C] = run;
    }
}

__global__ __launch_bounds__(256) void k_hscan_add(const float* __restrict__ in,
                                                   float* __restrict__ out)
{
    int idx = blockIdx.x * 256 + threadIdx.x;
    int wc = idx & (W * C - 1);
    int b  = idx >> 14;
    const float* p = in + (size_t)b * H * W * C + wc;
    float* q = out + (size_t)b * H * W * C + wc;
    float run = -FLT_MAX;
    for (int h = H - 1; h >= 0; --h) {
        run = fmaxf(run, p[(size_t)h * W * C]);
        q[(size_t)h * W * C] += run;
    }
}

extern "C" void kernel_launch(void* const* d_in, const int* in_sizes, int n_in,
                              void* d_out, int out_size, void* d_ws, size_t ws_size,
                              hipStream_t stream)
{
    const float* in = (const float*)d_in[0];
    float* out = (float*)d_out;

    const size_t need = (size_t)B * NT * W * C * sizeof(float);   // 32 MiB

    if (ws_size >= need) {
        float* hSuf = (float*)d_ws;
        k_colscan<<<B * 16, 256, 0, stream>>>(in, hSuf);
        k_fuse<<<B * NT, 512, 0, stream>>>(in, hSuf, out);
    } else {
        k_wscan<<<B * H * C / 256, 256, 0, stream>>>(in, out);
        k_hscan_add<<<B * W * C / 256, 256, 0, stream>>>(in, out);
    }
}